// Round 5
// baseline (410.397 us; speedup 1.0000x reference)
//
#include <hip/hip_runtime.h>
#include <hip/hip_bf16.h>
#include <math.h>

#define HID 256
typedef __attribute__((ext_vector_type(8))) short s16x8;
typedef __attribute__((ext_vector_type(4))) float f32x4;

__device__ __forceinline__ ushort f2bf(float f){
    uint u = __float_as_uint(f);
    u += 0x7FFF + ((u>>16)&1);
    return (ushort)(u>>16);
}
__device__ __forceinline__ float bf2f(ushort b){
    return __uint_as_float(((uint)b)<<16);
}
__device__ __forceinline__ float4 bf4_to_f4(ushort4 u){
    return make_float4(bf2f(u.x), bf2f(u.y), bf2f(u.z), bf2f(u.w));
}

// gelu tanh-approx, tanh via fast exp: tanh(u) = 1 - 2/(1+exp(2u))
__device__ __forceinline__ float gelu_tanh(float x){
    float u = 0.7978845608028654f*(x + 0.044715f*x*x*x);
    float t = 1.0f - 2.0f/(1.0f + __expf(2.0f*u));
    return 0.5f*x*(1.0f+t);
}

__global__ void k_count(const int* __restrict__ dst, int* __restrict__ cnt, int E){
    int e = blockIdx.x*blockDim.x + threadIdx.x;
    if(e<E) atomicAdd(&cnt[dst[e]], 1);
}

__global__ __launch_bounds__(256) void k_scan1(const int* __restrict__ cnt,
    int* __restrict__ tsum, int* __restrict__ bsum, int N){
    __shared__ int sm[256];
    int t = threadIdx.x, b = blockIdx.x;
    int base = b*1024 + t*4;
    int c0=0,c1=0,c2=0,c3=0;
    if(base+3 < N){
        int4 c = *reinterpret_cast<const int4*>(&cnt[base]);
        c0=c.x; c1=c.y; c2=c.z; c3=c.w;
    }else{
        if(base  <N) c0=cnt[base];
        if(base+1<N) c1=cnt[base+1];
        if(base+2<N) c2=cnt[base+2];
        if(base+3<N) c3=cnt[base+3];
    }
    int s = c0+c1+c2+c3;
    sm[t]=s; __syncthreads();
    for(int off=1; off<256; off<<=1){
        int v = sm[t];
        int a = (t>=off)? sm[t-off] : 0;
        __syncthreads();
        sm[t] = v+a;
        __syncthreads();
    }
    tsum[b*256+t] = sm[t]-s;
    if(t==255) bsum[b] = sm[255];
}

__global__ void k_scan2(const int* __restrict__ bsum, int* __restrict__ boff,
    int* __restrict__ indptr, int B, int N){
    if(threadIdx.x==0 && blockIdx.x==0){
        int run=0;
        for(int i=0;i<B;i++){ boff[i]=run; run+=bsum[i]; }
        indptr[N]=run;
    }
}

__global__ __launch_bounds__(256) void k_scan3(const int* __restrict__ cnt,
    const int* __restrict__ tsum, const int* __restrict__ boff,
    int* __restrict__ indptr, int* __restrict__ cursor, float* __restrict__ dinv, int N){
    int t = threadIdx.x, b = blockIdx.x;
    int base = b*1024 + t*4;
    int run = boff[b] + tsum[b*256+t];
    #pragma unroll
    for(int i=0;i<4;i++){
        int idx = base+i;
        if(idx<N){
            int c = cnt[idx];
            indptr[idx]=run; cursor[idx]=run;
            dinv[idx] = rsqrtf((float)(c+1));
            run += c;
        }
    }
}

__global__ void k_fill(const int* __restrict__ src, const int* __restrict__ dst,
    int* __restrict__ cursor, int* __restrict__ csr, int E){
    int e = blockIdx.x*blockDim.x + threadIdx.x;
    if(e<E){
        int pos = atomicAdd(&cursor[dst[e]], 1);
        csr[pos] = src[e];
    }
}

// W [K][256] fp32 -> fragment-shuffled bf16: Wb[((kb*256+n)*4+hi)*8+ii], k = kb*32+hi*8+ii
__global__ void k_cvt_win(const float* __restrict__ W, ushort* __restrict__ Wb){
    int i = blockIdx.x*blockDim.x + threadIdx.x;
    if(i >= 128*256) return;
    int k = i >> 8, n = i & 255;
    int kb = k>>5, hi=(k>>3)&3, ii=k&7;
    Wb[((kb*256+n)*4+hi)*8 + ii] = f2bf(W[i]);
}
__global__ void k_cvt_wc(const float* __restrict__ W, ushort* __restrict__ Wb){
    int i = blockIdx.x*blockDim.x + threadIdx.x;
    if(i >= 6*65536) return;
    int l = i >> 16;
    int k = (i>>8)&255, n = i&255;
    int kb = k>>5, hi=(k>>3)&3, ii=k&7;
    Wb[l*65536 + ((kb*256+n)*4+hi)*8 + ii] = f2bf(W[i]);
}

// shared epilogue: bias+gelu+LN (+blend), writes h0b/xcur/xs_out
template<bool INPUT>
__device__ __forceinline__ void epilogue(f32x4 (&acc)[2][4],
    const float* __restrict__ bp, const float* __restrict__ gp, const float* __restrict__ bep,
    const float* __restrict__ dinv, ushort* __restrict__ h0b,
    float* __restrict__ xcur, ushort* __restrict__ xs_out,
    int row0, int wc, int lr, int hi, int N,
    float (*sm1)[4], float (*sm2)[4])
{
    float bcv[4], gcv[4], bev[4];
    #pragma unroll
    for(int nf=0;nf<4;nf++){
        int col = wc*64 + nf*16 + lr;
        bcv[nf]=bp[col]; gcv[nf]=gp[col]; bev[nf]=bep[col];
    }
    #pragma unroll
    for(int m=0;m<2;m++){
        #pragma unroll
        for(int r=0;r<4;r++){
            float ls1=0.f, ls2=0.f;
            #pragma unroll
            for(int nf=0;nf<4;nf++){
                float t = gelu_tanh(acc[m][nf][r] + bcv[nf]);
                acc[m][nf][r] = t;
                ls1 += t; ls2 += t*t;
            }
            #pragma unroll
            for(int off=1; off<16; off<<=1){
                ls1 += __shfl_xor(ls1, off, 64);
                ls2 += __shfl_xor(ls2, off, 64);
            }
            if(lr==0){
                int row = m*16 + hi*4 + r;
                sm1[row][wc]=ls1; sm2[row][wc]=ls2;
            }
        }
    }
    __syncthreads();
    #pragma unroll
    for(int m=0;m<2;m++){
        #pragma unroll
        for(int r=0;r<4;r++){
            int row = m*16 + hi*4 + r;
            int grow = row0 + row;
            if(grow >= N) continue;
            float S1 = sm1[row][0]+sm1[row][1]+sm1[row][2]+sm1[row][3];
            float S2 = sm2[row][0]+sm2[row][1]+sm2[row][2]+sm2[row][3];
            float mu = S1*(1.0f/256.0f);
            float var = fmaxf(S2*(1.0f/256.0f) - mu*mu, 0.0f);
            float rs = rsqrtf(var + 1e-5f);
            float dv = dinv[grow];
            #pragma unroll
            for(int nf=0;nf<4;nf++){
                int col = wc*64 + nf*16 + lr;
                size_t idx = (size_t)grow*HID + col;
                float o = (acc[m][nf][r]-mu)*rs*gcv[nf] + bev[nf];
                if(INPUT){
                    h0b[idx] = f2bf(o);
                    xcur[idx] = o;
                    xs_out[idx] = f2bf(dv*o);
                }else{
                    float h = bf2f(h0b[idx]);
                    float xc = xcur[idx] + 0.9f*o + 0.1f*h;
                    xcur[idx] = xc;
                    xs_out[idx] = f2bf(dv*xc);
                }
            }
        }
    }
}

// input block: reads fp32 X[N][128] directly, converts fragments in-reg
__global__ __launch_bounds__(256) void k_gemm_in(const float* __restrict__ X,
    const ushort* __restrict__ Wb,
    const float* __restrict__ bp, const float* __restrict__ gp, const float* __restrict__ bep,
    const float* __restrict__ dinv, ushort* __restrict__ h0b,
    float* __restrict__ xcur, ushort* __restrict__ xs_out, int N)
{
    const int lane = threadIdx.x & 63;
    const int wc = threadIdx.x >> 6;
    const int lr = lane & 15;
    const int hi = lane >> 4;
    const int row0 = blockIdx.x*32;
    __shared__ float sm1[32][4];
    __shared__ float sm2[32][4];

    f32x4 acc[2][4];
    #pragma unroll
    for(int m=0;m<2;m++)
        #pragma unroll
        for(int n=0;n<4;n++){ acc[m][n].x=0.f; acc[m][n].y=0.f; acc[m][n].z=0.f; acc[m][n].w=0.f; }

    int r0 = row0 + lr;      if(r0 >= N) r0 = N-1;
    int r1 = row0 + 16 + lr; if(r1 >= N) r1 = N-1;
    const float* xp0 = X + (size_t)r0*128 + hi*8;
    const float* xp1 = X + (size_t)r1*128 + hi*8;
    const ushort* bpp = Wb + (wc*64 + lr)*32 + hi*8;

    #pragma unroll
    for(int kb=0; kb<4; kb++){
        float4 p0a = *reinterpret_cast<const float4*>(xp0 + kb*32);
        float4 p0b = *reinterpret_cast<const float4*>(xp0 + kb*32 + 4);
        float4 p1a = *reinterpret_cast<const float4*>(xp1 + kb*32);
        float4 p1b = *reinterpret_cast<const float4*>(xp1 + kb*32 + 4);
        s16x8 a0, a1;
        a0[0]=(short)f2bf(p0a.x); a0[1]=(short)f2bf(p0a.y); a0[2]=(short)f2bf(p0a.z); a0[3]=(short)f2bf(p0a.w);
        a0[4]=(short)f2bf(p0b.x); a0[5]=(short)f2bf(p0b.y); a0[6]=(short)f2bf(p0b.z); a0[7]=(short)f2bf(p0b.w);
        a1[0]=(short)f2bf(p1a.x); a1[1]=(short)f2bf(p1a.y); a1[2]=(short)f2bf(p1a.z); a1[3]=(short)f2bf(p1a.w);
        a1[4]=(short)f2bf(p1b.x); a1[5]=(short)f2bf(p1b.y); a1[6]=(short)f2bf(p1b.z); a1[7]=(short)f2bf(p1b.w);
        #pragma unroll
        for(int nf=0;nf<4;nf++){
            s16x8 b = *reinterpret_cast<const s16x8*>(bpp + kb*8192 + nf*512);
            acc[0][nf] = __builtin_amdgcn_mfma_f32_16x16x32_bf16(a0, b, acc[0][nf], 0,0,0);
            acc[1][nf] = __builtin_amdgcn_mfma_f32_16x16x32_bf16(a1, b, acc[1][nf], 0,0,0);
        }
    }
    epilogue<true>(acc, bp, gp, bep, dinv, h0b, xcur, xs_out, row0, wc, lr, hi, N, sm1, sm2);
}

// conv layer: fused gather (CSR) + GEMM + bias/gelu/LN/blend
__global__ __launch_bounds__(256) void k_conv(const ushort* __restrict__ xs_in,
    const ushort* __restrict__ Wb,
    const int* __restrict__ indptr, const int* __restrict__ csr,
    const float* __restrict__ dinv,
    const float* __restrict__ bp, const float* __restrict__ gp, const float* __restrict__ bep,
    ushort* __restrict__ h0b, float* __restrict__ xcur,
    ushort* __restrict__ xs_out, int N)
{
    __shared__ ushort yls[32*256];   // 16 KB, XOR-swizzled rows
    __shared__ float sm1[32][4];
    __shared__ float sm2[32][4];
    const int lane = threadIdx.x & 63;
    const int wc = threadIdx.x >> 6;
    const int lr = lane & 15;
    const int hi = lane >> 4;
    const int row0 = blockIdx.x*32;

    // ---- gather phase: this wave handles rows wc*8 .. wc*8+7 ----
    const ushort4* X4 = reinterpret_cast<const ushort4*>(xs_in);
    char* ybase = (char*)yls;
    #pragma unroll 1
    for(int i=0;i<8;i++){
        int li = wc*8 + i;
        int n = row0 + li;
        if(n >= N) n = N-1;
        float4 acc = bf4_to_f4(X4[(size_t)n*64 + lane]);
        int e0 = indptr[n], e1 = indptr[n+1];
        int e = e0;
        for(; e+4<=e1; e+=4){
            int i0=csr[e], i1=csr[e+1], i2=csr[e+2], i3=csr[e+3];
            float4 v0 = bf4_to_f4(X4[(size_t)i0*64+lane]);
            float4 v1 = bf4_to_f4(X4[(size_t)i1*64+lane]);
            float4 v2 = bf4_to_f4(X4[(size_t)i2*64+lane]);
            float4 v3 = bf4_to_f4(X4[(size_t)i3*64+lane]);
            acc.x += (v0.x+v1.x)+(v2.x+v3.x);
            acc.y += (v0.y+v1.y)+(v2.y+v3.y);
            acc.z += (v0.z+v1.z)+(v2.z+v3.z);
            acc.w += (v0.w+v1.w)+(v2.w+v3.w);
        }
        for(; e<e1; e++){
            float4 v = bf4_to_f4(X4[(size_t)csr[e]*64+lane]);
            acc.x+=v.x; acc.y+=v.y; acc.z+=v.z; acc.w+=v.w;
        }
        float dn = dinv[n];
        ushort4 o; o.x=f2bf(dn*acc.x); o.y=f2bf(dn*acc.y); o.z=f2bf(dn*acc.z); o.w=f2bf(dn*acc.w);
        // row li, col-bytes lane*8..lane*8+7, XOR-swizzled
        *reinterpret_cast<ushort4*>(ybase + li*512 + ((lane*8) ^ ((li&7)<<4))) = o;
    }
    __syncthreads();

    // ---- GEMM phase: A from LDS (swizzled), B from global (frag-shuffled) ----
    f32x4 acc[2][4];
    #pragma unroll
    for(int m=0;m<2;m++)
        #pragma unroll
        for(int n=0;n<4;n++){ acc[m][n].x=0.f; acc[m][n].y=0.f; acc[m][n].z=0.f; acc[m][n].w=0.f; }

    const ushort* bpp = Wb + (wc*64 + lr)*32 + hi*8;
    s16x8 bb[2][4];
    #pragma unroll
    for(int nf=0;nf<4;nf++) bb[0][nf] = *reinterpret_cast<const s16x8*>(bpp + nf*512);

    const int sws = (lr&7)<<4;
    #pragma unroll
    for(int kb=0; kb<8; kb++){
        const int cur = kb&1, nxt = cur^1;
        if(kb < 7){
            #pragma unroll
            for(int nf=0;nf<4;nf++)
                bb[nxt][nf] = *reinterpret_cast<const s16x8*>(bpp + (kb+1)*8192 + nf*512);
        }
        int cb = kb*64 + hi*16;
        s16x8 a0 = *reinterpret_cast<const s16x8*>(ybase + lr*512        + (cb ^ sws));
        s16x8 a1 = *reinterpret_cast<const s16x8*>(ybase + (16+lr)*512   + (cb ^ sws));
        #pragma unroll
        for(int nf=0;nf<4;nf++){
            acc[0][nf] = __builtin_amdgcn_mfma_f32_16x16x32_bf16(a0, bb[cur][nf], acc[0][nf], 0,0,0);
            acc[1][nf] = __builtin_amdgcn_mfma_f32_16x16x32_bf16(a1, bb[cur][nf], acc[1][nf], 0,0,0);
        }
    }
    __syncthreads();  // yls reads done before epilogue reuses LDS-barrier pattern
    epilogue<false>(acc, bp, gp, bep, dinv, h0b, xcur, xs_out, row0, wc, lr, hi, N, sm1, sm2);
}

extern "C" void kernel_launch(void* const* d_in, const int* in_sizes, int n_in,
                              void* d_out, int out_size, void* d_ws, size_t ws_size,
                              hipStream_t stream){
    const float* x     = (const float*)d_in[0];
    const int*   ei    = (const int*)d_in[1];
    const float* W_in  = (const float*)d_in[2];
    const float* b_in  = (const float*)d_in[3];
    const float* g_in  = (const float*)d_in[4];
    const float* be_in = (const float*)d_in[5];
    const float* Wc    = (const float*)d_in[6];
    const float* bc    = (const float*)d_in[7];
    const float* gc    = (const float*)d_in[8];
    const float* bec   = (const float*)d_in[9];
    const int N = in_sizes[0]/128;
    const int E = in_sizes[1]/2;
    const int* src = ei;
    const int* dst = ei + E;
    float* xcur = (float*)d_out;
    const int B = (N+1023)/1024;

    char* w = (char*)d_ws;
    ushort* xs0  = (ushort*)w; w += (size_t)N*HID*2;
    ushort* xs1  = (ushort*)w; w += (size_t)N*HID*2;
    ushort* h0b  = (ushort*)w; w += (size_t)N*HID*2;
    ushort* wbin = (ushort*)w; w += (size_t)128*256*2;
    ushort* wbc  = (ushort*)w; w += (size_t)6*65536*2;
    float* dinv  = (float*)w;  w += (size_t)N*4;
    int* cnt     = (int*)w;    w += (size_t)N*4;
    int* cursor  = (int*)w;    w += (size_t)N*4;
    int* csr     = (int*)w;    w += (size_t)E*4;
    int* indptr  = (int*)w;    w += (size_t)(N+1)*4;
    int* tsum    = (int*)w;    w += (size_t)B*256*4;
    int* bsum    = (int*)w;    w += (size_t)B*4;
    int* boff    = (int*)w;    w += (size_t)B*4;

    (void)hipMemsetAsync(cnt, 0, (size_t)N*4, stream);
    k_count<<<(E+255)/256,256,0,stream>>>(dst,cnt,E);
    k_scan1<<<B,256,0,stream>>>(cnt, tsum, bsum, N);
    k_scan2<<<1,64,0,stream>>>(bsum, boff, indptr, B, N);
    k_scan3<<<B,256,0,stream>>>(cnt, tsum, boff, indptr, cursor, dinv, N);
    k_fill<<<(E+255)/256,256,0,stream>>>(src,dst,cursor,csr,E);

    k_cvt_win<<<(128*256+255)/256,256,0,stream>>>(W_in, wbin);
    k_cvt_wc<<<(6*65536+255)/256,256,0,stream>>>(Wc, wbc);

    const int GB = (N+31)/32;
    k_gemm_in<<<GB,256,0,stream>>>(x, wbin, b_in, g_in, be_in, dinv, h0b, xcur, xs0, N);
    ushort* xsA = xs0;
    ushort* xsB = xs1;
    for(int l=0;l<6;l++){
        k_conv<<<GB,256,0,stream>>>(xsA, wbc+(size_t)l*65536, indptr, csr, dinv,
            bc+(size_t)l*HID, gc+(size_t)l*HID, bec+(size_t)l*HID,
            h0b, xcur, xsB, N);
        ushort* t = xsA; xsA = xsB; xsB = t;
    }
}

// Round 6
// 351.658 us; speedup vs baseline: 1.1670x; 1.1670x over previous
//
#include <hip/hip_runtime.h>
#include <hip/hip_bf16.h>
#include <math.h>

#define HID 256
typedef __attribute__((ext_vector_type(8))) short s16x8;
typedef __attribute__((ext_vector_type(4))) float f32x4;

__device__ __forceinline__ ushort f2bf(float f){
    uint u = __float_as_uint(f);
    u += 0x7FFF + ((u>>16)&1);
    return (ushort)(u>>16);
}
__device__ __forceinline__ float bf2f(ushort b){
    return __uint_as_float(((uint)b)<<16);
}
__device__ __forceinline__ float4 bf4_to_f4(ushort4 u){
    return make_float4(bf2f(u.x), bf2f(u.y), bf2f(u.z), bf2f(u.w));
}

// gelu tanh-approx, tanh via fast exp: tanh(u) = 1 - 2/(1+exp(2u))
__device__ __forceinline__ float gelu_tanh(float x){
    float u = 0.7978845608028654f*(x + 0.044715f*x*x*x);
    float t = 1.0f - 2.0f/(1.0f + __expf(2.0f*u));
    return 0.5f*x*(1.0f+t);
}

__global__ void k_count(const int* __restrict__ dst, int* __restrict__ cnt, int E){
    int e = blockIdx.x*blockDim.x + threadIdx.x;
    if(e<E) atomicAdd(&cnt[dst[e]], 1);
}

__global__ __launch_bounds__(256) void k_scan1(const int* __restrict__ cnt,
    int* __restrict__ tsum, int* __restrict__ bsum, int N){
    __shared__ int sm[256];
    int t = threadIdx.x, b = blockIdx.x;
    int base = b*1024 + t*4;
    int c0=0,c1=0,c2=0,c3=0;
    if(base+3 < N){
        int4 c = *reinterpret_cast<const int4*>(&cnt[base]);
        c0=c.x; c1=c.y; c2=c.z; c3=c.w;
    }else{
        if(base  <N) c0=cnt[base];
        if(base+1<N) c1=cnt[base+1];
        if(base+2<N) c2=cnt[base+2];
        if(base+3<N) c3=cnt[base+3];
    }
    int s = c0+c1+c2+c3;
    sm[t]=s; __syncthreads();
    for(int off=1; off<256; off<<=1){
        int v = sm[t];
        int a = (t>=off)? sm[t-off] : 0;
        __syncthreads();
        sm[t] = v+a;
        __syncthreads();
    }
    tsum[b*256+t] = sm[t]-s;
    if(t==255) bsum[b] = sm[255];
}

__global__ void k_scan2(const int* __restrict__ bsum, int* __restrict__ boff,
    int* __restrict__ indptr, int B, int N){
    if(threadIdx.x==0 && blockIdx.x==0){
        int run=0;
        for(int i=0;i<B;i++){ boff[i]=run; run+=bsum[i]; }
        indptr[N]=run;
    }
}

__global__ __launch_bounds__(256) void k_scan3(const int* __restrict__ cnt,
    const int* __restrict__ tsum, const int* __restrict__ boff,
    int* __restrict__ indptr, int* __restrict__ cursor, float* __restrict__ dinv, int N){
    int t = threadIdx.x, b = blockIdx.x;
    int base = b*1024 + t*4;
    int run = boff[b] + tsum[b*256+t];
    #pragma unroll
    for(int i=0;i<4;i++){
        int idx = base+i;
        if(idx<N){
            int c = cnt[idx];
            indptr[idx]=run; cursor[idx]=run;
            dinv[idx] = rsqrtf((float)(c+1));
            run += c;
        }
    }
}

__global__ void k_fill(const int* __restrict__ src, const int* __restrict__ dst,
    int* __restrict__ cursor, int* __restrict__ csr, int E){
    int e = blockIdx.x*blockDim.x + threadIdx.x;
    if(e<E){
        int pos = atomicAdd(&cursor[dst[e]], 1);
        csr[pos] = src[e];
    }
}

// W [K][256] fp32 -> fragment-shuffled bf16: Wb[((kb*256+n)*4+hi)*8+ii], k = kb*32+hi*8+ii
__global__ void k_cvt_win(const float* __restrict__ W, ushort* __restrict__ Wb){
    int i = blockIdx.x*blockDim.x + threadIdx.x;
    if(i >= 128*256) return;
    int k = i >> 8, n = i & 255;
    int kb = k>>5, hi=(k>>3)&3, ii=k&7;
    Wb[((kb*256+n)*4+hi)*8 + ii] = f2bf(W[i]);
}
__global__ void k_cvt_wc(const float* __restrict__ W, ushort* __restrict__ Wb){
    int i = blockIdx.x*blockDim.x + threadIdx.x;
    if(i >= 6*65536) return;
    int l = i >> 16;
    int k = (i>>8)&255, n = i&255;
    int kb = k>>5, hi=(k>>3)&3, ii=k&7;
    Wb[l*65536 + ((kb*256+n)*4+hi)*8 + ii] = f2bf(W[i]);
}

// gather: yb[n] = bf16( dinv[n] * (xsc[n] + sum_{e in CSR[n]} xsc[src_e]) ), 8-deep MLP
__global__ __launch_bounds__(256) void k_agg(const ushort* __restrict__ xsc,
    const int* __restrict__ indptr, const int* __restrict__ csr,
    const float* __restrict__ dinv, ushort* __restrict__ yb, int N)
{
    int wave = threadIdx.x>>6, lane = threadIdx.x&63;
    int n = blockIdx.x*4 + wave;
    if(n>=N) return;
    const ushort4* X4 = reinterpret_cast<const ushort4*>(xsc);
    float4 acc = bf4_to_f4(X4[(size_t)n*64+lane]);
    int e0 = indptr[n], e1 = indptr[n+1];
    int e = e0;
    for(; e+8<=e1; e+=8){
        int idx[8];
        #pragma unroll
        for(int q=0;q<8;q++) idx[q]=csr[e+q];
        float4 v[8];
        #pragma unroll
        for(int q=0;q<8;q++) v[q]=bf4_to_f4(X4[(size_t)idx[q]*64+lane]);
        #pragma unroll
        for(int q=0;q<8;q++){
            acc.x+=v[q].x; acc.y+=v[q].y; acc.z+=v[q].z; acc.w+=v[q].w;
        }
    }
    if(e+4<=e1){
        int i0=csr[e], i1=csr[e+1], i2=csr[e+2], i3=csr[e+3];
        float4 v0 = bf4_to_f4(X4[(size_t)i0*64+lane]);
        float4 v1 = bf4_to_f4(X4[(size_t)i1*64+lane]);
        float4 v2 = bf4_to_f4(X4[(size_t)i2*64+lane]);
        float4 v3 = bf4_to_f4(X4[(size_t)i3*64+lane]);
        acc.x += (v0.x+v1.x)+(v2.x+v3.x);
        acc.y += (v0.y+v1.y)+(v2.y+v3.y);
        acc.z += (v0.z+v1.z)+(v2.z+v3.z);
        acc.w += (v0.w+v1.w)+(v2.w+v3.w);
        e += 4;
    }
    for(; e<e1; e++){
        float4 v = bf4_to_f4(X4[(size_t)csr[e]*64+lane]);
        acc.x+=v.x; acc.y+=v.y; acc.z+=v.z; acc.w+=v.w;
    }
    float dn = dinv[n];
    ushort4 o; o.x=f2bf(dn*acc.x); o.y=f2bf(dn*acc.y); o.z=f2bf(dn*acc.z); o.w=f2bf(dn*acc.w);
    reinterpret_cast<ushort4*>(yb)[(size_t)n*64+lane] = o;
}

// shared epilogue for 16-row tiles: bias+gelu+LN (+blend), writes h0b/xcur/xs_out
template<bool INPUT>
__device__ __forceinline__ void epilogue16(f32x4 (&acc)[4],
    const float* __restrict__ bp, const float* __restrict__ gp, const float* __restrict__ bep,
    const float* __restrict__ dinv, ushort* __restrict__ h0b,
    float* __restrict__ xcur, ushort* __restrict__ xs_out,
    int row0, int wc, int lr, int hi, int N,
    float (*sm1)[4], float (*sm2)[4])
{
    float bcv[4], gcv[4], bev[4];
    #pragma unroll
    for(int nf=0;nf<4;nf++){
        int col = wc*64 + nf*16 + lr;
        bcv[nf]=bp[col]; gcv[nf]=gp[col]; bev[nf]=bep[col];
    }
    #pragma unroll
    for(int r=0;r<4;r++){
        float ls1=0.f, ls2=0.f;
        #pragma unroll
        for(int nf=0;nf<4;nf++){
            float t = gelu_tanh(acc[nf][r] + bcv[nf]);
            acc[nf][r] = t;
            ls1 += t; ls2 += t*t;
        }
        #pragma unroll
        for(int off=1; off<16; off<<=1){
            ls1 += __shfl_xor(ls1, off, 64);
            ls2 += __shfl_xor(ls2, off, 64);
        }
        if(lr==0){
            int row = hi*4 + r;
            sm1[row][wc]=ls1; sm2[row][wc]=ls2;
        }
    }
    __syncthreads();
    #pragma unroll
    for(int r=0;r<4;r++){
        int row = hi*4 + r;
        int grow = row0 + row;
        if(grow >= N) continue;
        float S1 = sm1[row][0]+sm1[row][1]+sm1[row][2]+sm1[row][3];
        float S2 = sm2[row][0]+sm2[row][1]+sm2[row][2]+sm2[row][3];
        float mu = S1*(1.0f/256.0f);
        float var = fmaxf(S2*(1.0f/256.0f) - mu*mu, 0.0f);
        float rs = rsqrtf(var + 1e-5f);
        float dv = dinv[grow];
        #pragma unroll
        for(int nf=0;nf<4;nf++){
            int col = wc*64 + nf*16 + lr;
            size_t idx = (size_t)grow*HID + col;
            float o = (acc[nf][r]-mu)*rs*gcv[nf] + bev[nf];
            if(INPUT){
                h0b[idx] = f2bf(o);
                xcur[idx] = o;
                xs_out[idx] = f2bf(dv*o);
            }else{
                float h = bf2f(h0b[idx]);
                float xc = xcur[idx] + 0.9f*o + 0.1f*h;
                xcur[idx] = xc;
                xs_out[idx] = f2bf(dv*xc);
            }
        }
    }
}

// input block: 16-row tiles, reads fp32 X[N][128] directly, converts fragments in-reg
__global__ __launch_bounds__(256) void k_gemm_in(const float* __restrict__ X,
    const ushort* __restrict__ Wb,
    const float* __restrict__ bp, const float* __restrict__ gp, const float* __restrict__ bep,
    const float* __restrict__ dinv, ushort* __restrict__ h0b,
    float* __restrict__ xcur, ushort* __restrict__ xs_out, int N)
{
    const int lane = threadIdx.x & 63;
    const int wc = threadIdx.x >> 6;
    const int lr = lane & 15;
    const int hi = lane >> 4;
    const int row0 = blockIdx.x*16;
    __shared__ float sm1[16][4];
    __shared__ float sm2[16][4];

    f32x4 acc[4];
    #pragma unroll
    for(int n=0;n<4;n++){ acc[n].x=0.f; acc[n].y=0.f; acc[n].z=0.f; acc[n].w=0.f; }

    int r0 = row0 + lr; if(r0 >= N) r0 = N-1;
    const float* xp0 = X + (size_t)r0*128 + hi*8;
    const ushort* bpp = Wb + (wc*64 + lr)*32 + hi*8;

    #pragma unroll
    for(int kb=0; kb<4; kb++){
        float4 p0a = *reinterpret_cast<const float4*>(xp0 + kb*32);
        float4 p0b = *reinterpret_cast<const float4*>(xp0 + kb*32 + 4);
        s16x8 a0;
        a0[0]=(short)f2bf(p0a.x); a0[1]=(short)f2bf(p0a.y); a0[2]=(short)f2bf(p0a.z); a0[3]=(short)f2bf(p0a.w);
        a0[4]=(short)f2bf(p0b.x); a0[5]=(short)f2bf(p0b.y); a0[6]=(short)f2bf(p0b.z); a0[7]=(short)f2bf(p0b.w);
        #pragma unroll
        for(int nf=0;nf<4;nf++){
            s16x8 b = *reinterpret_cast<const s16x8*>(bpp + kb*8192 + nf*512);
            acc[nf] = __builtin_amdgcn_mfma_f32_16x16x32_bf16(a0, b, acc[nf], 0,0,0);
        }
    }
    epilogue16<true>(acc, bp, gp, bep, dinv, h0b, xcur, xs_out, row0, wc, lr, hi, N, sm1, sm2);
}

// conv GEMM: 16-row tiles, A = yb (aggregated bf16), fused bias/gelu/LN/blend
__global__ __launch_bounds__(256) void k_gemm_fused(const ushort* __restrict__ A,
    const ushort* __restrict__ Wb,
    const float* __restrict__ bp, const float* __restrict__ gp, const float* __restrict__ bep,
    const float* __restrict__ dinv, ushort* __restrict__ h0b,
    float* __restrict__ xcur, ushort* __restrict__ xs_out, int N)
{
    const int lane = threadIdx.x & 63;
    const int wc = threadIdx.x >> 6;
    const int lr = lane & 15;
    const int hi = lane >> 4;
    const int row0 = blockIdx.x*16;
    __shared__ float sm1[16][4];
    __shared__ float sm2[16][4];

    f32x4 acc[4];
    #pragma unroll
    for(int n=0;n<4;n++){ acc[n].x=0.f; acc[n].y=0.f; acc[n].z=0.f; acc[n].w=0.f; }

    int r0 = row0 + lr; if(r0 >= N) r0 = N-1;
    const ushort* ap0 = A + (size_t)r0*256 + hi*8;
    const ushort* bpp = Wb + (wc*64 + lr)*32 + hi*8;

    s16x8 a0[2], bb[2][4];
    a0[0] = *reinterpret_cast<const s16x8*>(ap0);
    #pragma unroll
    for(int nf=0;nf<4;nf++) bb[0][nf] = *reinterpret_cast<const s16x8*>(bpp + nf*512);

    #pragma unroll
    for(int kb=0; kb<8; kb++){
        const int cur = kb&1, nxt = cur^1;
        if(kb < 7){
            a0[nxt] = *reinterpret_cast<const s16x8*>(ap0 + (kb+1)*32);
            #pragma unroll
            for(int nf=0;nf<4;nf++)
                bb[nxt][nf] = *reinterpret_cast<const s16x8*>(bpp + (kb+1)*8192 + nf*512);
        }
        #pragma unroll
        for(int nf=0;nf<4;nf++)
            acc[nf] = __builtin_amdgcn_mfma_f32_16x16x32_bf16(a0[cur], bb[cur][nf], acc[nf], 0,0,0);
    }
    epilogue16<false>(acc, bp, gp, bep, dinv, h0b, xcur, xs_out, row0, wc, lr, hi, N, sm1, sm2);
}

extern "C" void kernel_launch(void* const* d_in, const int* in_sizes, int n_in,
                              void* d_out, int out_size, void* d_ws, size_t ws_size,
                              hipStream_t stream){
    const float* x     = (const float*)d_in[0];
    const int*   ei    = (const int*)d_in[1];
    const float* W_in  = (const float*)d_in[2];
    const float* b_in  = (const float*)d_in[3];
    const float* g_in  = (const float*)d_in[4];
    const float* be_in = (const float*)d_in[5];
    const float* Wc    = (const float*)d_in[6];
    const float* bc    = (const float*)d_in[7];
    const float* gc    = (const float*)d_in[8];
    const float* bec   = (const float*)d_in[9];
    const int N = in_sizes[0]/128;
    const int E = in_sizes[1]/2;
    const int* src = ei;
    const int* dst = ei + E;
    float* xcur = (float*)d_out;
    const int B = (N+1023)/1024;

    char* w = (char*)d_ws;
    ushort* xsc  = (ushort*)w; w += (size_t)N*HID*2;
    ushort* yb   = (ushort*)w; w += (size_t)N*HID*2;
    ushort* h0b  = (ushort*)w; w += (size_t)N*HID*2;
    ushort* wbin = (ushort*)w; w += (size_t)128*256*2;
    ushort* wbc  = (ushort*)w; w += (size_t)6*65536*2;
    float* dinv  = (float*)w;  w += (size_t)N*4;
    int* cnt     = (int*)w;    w += (size_t)N*4;
    int* cursor  = (int*)w;    w += (size_t)N*4;
    int* csr     = (int*)w;    w += (size_t)E*4;
    int* indptr  = (int*)w;    w += (size_t)(N+1)*4;
    int* tsum    = (int*)w;    w += (size_t)B*256*4;
    int* bsum    = (int*)w;    w += (size_t)B*4;
    int* boff    = (int*)w;    w += (size_t)B*4;

    (void)hipMemsetAsync(cnt, 0, (size_t)N*4, stream);
    k_count<<<(E+255)/256,256,0,stream>>>(dst,cnt,E);
    k_scan1<<<B,256,0,stream>>>(cnt, tsum, bsum, N);
    k_scan2<<<1,64,0,stream>>>(bsum, boff, indptr, B, N);
    k_scan3<<<B,256,0,stream>>>(cnt, tsum, boff, indptr, cursor, dinv, N);
    k_fill<<<(E+255)/256,256,0,stream>>>(src,dst,cursor,csr,E);

    k_cvt_win<<<(128*256+255)/256,256,0,stream>>>(W_in, wbin);
    k_cvt_wc<<<(6*65536+255)/256,256,0,stream>>>(Wc, wbc);

    const int GB = (N+15)/16;
    k_gemm_in<<<GB,256,0,stream>>>(x, wbin, b_in, g_in, be_in, dinv, h0b, xcur, xsc, N);
    for(int l=0;l<6;l++){
        k_agg<<<(N+3)/4,256,0,stream>>>(xsc, indptr, csr, dinv, yb, N);
        k_gemm_fused<<<GB,256,0,stream>>>(yb, wbc+(size_t)l*65536,
            bc+(size_t)l*HID, gc+(size_t)l*HID, bec+(size_t)l*HID,
            dinv, h0b, xcur, xsc, N);
    }
}

// Round 7
// 336.081 us; speedup vs baseline: 1.2211x; 1.0463x over previous
//
#include <hip/hip_runtime.h>
#include <hip/hip_bf16.h>
#include <math.h>

#define HID 256
typedef __attribute__((ext_vector_type(8))) short s16x8;
typedef __attribute__((ext_vector_type(4))) float f32x4;

__device__ __forceinline__ ushort f2bf(float f){
    uint u = __float_as_uint(f);
    u += 0x7FFF + ((u>>16)&1);
    return (ushort)(u>>16);
}
__device__ __forceinline__ float bf2f(ushort b){
    return __uint_as_float(((uint)b)<<16);
}
__device__ __forceinline__ float4 bf4_to_f4(ushort4 u){
    return make_float4(bf2f(u.x), bf2f(u.y), bf2f(u.z), bf2f(u.w));
}

// gelu tanh-approx, tanh via fast exp: tanh(u) = 1 - 2/(1+exp(2u))
__device__ __forceinline__ float gelu_tanh(float x){
    float u = 0.7978845608028654f*(x + 0.044715f*x*x*x);
    float t = 1.0f - 2.0f/(1.0f + __expf(2.0f*u));
    return 0.5f*x*(1.0f+t);
}

__global__ void k_count(const int* __restrict__ dst, int* __restrict__ cnt, int E){
    int e = blockIdx.x*blockDim.x + threadIdx.x;
    if(e<E) atomicAdd(&cnt[dst[e]], 1);
}

__global__ __launch_bounds__(256) void k_scan1(const int* __restrict__ cnt,
    int* __restrict__ tsum, int* __restrict__ bsum, int N){
    __shared__ int sm[256];
    int t = threadIdx.x, b = blockIdx.x;
    int base = b*1024 + t*4;
    int c0=0,c1=0,c2=0,c3=0;
    if(base+3 < N){
        int4 c = *reinterpret_cast<const int4*>(&cnt[base]);
        c0=c.x; c1=c.y; c2=c.z; c3=c.w;
    }else{
        if(base  <N) c0=cnt[base];
        if(base+1<N) c1=cnt[base+1];
        if(base+2<N) c2=cnt[base+2];
        if(base+3<N) c3=cnt[base+3];
    }
    int s = c0+c1+c2+c3;
    sm[t]=s; __syncthreads();
    for(int off=1; off<256; off<<=1){
        int v = sm[t];
        int a = (t>=off)? sm[t-off] : 0;
        __syncthreads();
        sm[t] = v+a;
        __syncthreads();
    }
    tsum[b*256+t] = sm[t]-s;
    if(t==255) bsum[b] = sm[255];
}

// scan3: each block sums bsum[0..b-1] itself (B<=20), writes indptr/cursor/dinv
__global__ __launch_bounds__(256) void k_scan3(const int* __restrict__ cnt,
    const int* __restrict__ tsum, const int* __restrict__ bsum,
    int* __restrict__ indptr, int* __restrict__ cursor, float* __restrict__ dinv,
    int N, int B){
    __shared__ int sboff, stot;
    int t = threadIdx.x, b = blockIdx.x;
    if(t==0){
        int run=0, tot=0;
        for(int i=0;i<B;i++){ int v=bsum[i]; if(i<b) run+=v; tot+=v; }
        sboff=run; stot=tot;
        if(b==0) indptr[N]=tot;
    }
    __syncthreads();
    int base = b*1024 + t*4;
    int run = sboff + tsum[b*256+t];
    #pragma unroll
    for(int i=0;i<4;i++){
        int idx = base+i;
        if(idx<N){
            int c = cnt[idx];
            indptr[idx]=run; cursor[idx]=run;
            dinv[idx] = rsqrtf((float)(c+1));
            run += c;
        }
    }
}

__global__ void k_fill(const int* __restrict__ src, const int* __restrict__ dst,
    int* __restrict__ cursor, int* __restrict__ csr, int E){
    int e = blockIdx.x*blockDim.x + threadIdx.x;
    if(e<E){
        int pos = atomicAdd(&cursor[dst[e]], 1);
        csr[pos] = src[e];
    }
}

// combined weight convert: W_in (128x256) + Wc (6x256x256), fragment-shuffled bf16
// layout: Wb[((kb*256+n)*4+hi)*8+ii], k = kb*32+hi*8+ii
__global__ void k_cvt_w(const float* __restrict__ Win, const float* __restrict__ Wc,
    ushort* __restrict__ wbin, ushort* __restrict__ wbc){
    int i = blockIdx.x*blockDim.x + threadIdx.x;
    if(i < 32768){
        int k = i >> 8, n = i & 255;
        int kb = k>>5, hi=(k>>3)&3, ii=k&7;
        wbin[((kb*256+n)*4+hi)*8 + ii] = f2bf(Win[i]);
    }else if(i < 32768 + 6*65536){
        int j = i - 32768;
        int l = j >> 16;
        int k = (j>>8)&255, n = j&255;
        int kb = k>>5, hi=(k>>3)&3, ii=k&7;
        wbc[l*65536 + ((kb*256+n)*4+hi)*8 + ii] = f2bf(Wc[j]);
    }
}

// gather: yb[n] = bf16( dinv[n] * (dinv[n]*x[n] + sum_{e} dinv[src]*x[src]) ), 8-deep MLP
__global__ __launch_bounds__(256) void k_agg(const ushort* __restrict__ xb,
    const int* __restrict__ indptr, const int* __restrict__ csr,
    const float* __restrict__ dinv, ushort* __restrict__ yb, int N)
{
    int wave = threadIdx.x>>6, lane = threadIdx.x&63;
    int n = blockIdx.x*4 + wave;
    if(n>=N) return;
    const ushort4* X4 = reinterpret_cast<const ushort4*>(xb);
    float dn = dinv[n];
    float4 sv = bf4_to_f4(X4[(size_t)n*64+lane]);
    float4 acc = make_float4(dn*sv.x, dn*sv.y, dn*sv.z, dn*sv.w);
    int e0 = indptr[n], e1 = indptr[n+1];
    int e = e0;
    for(; e+8<=e1; e+=8){
        int idx[8];
        #pragma unroll
        for(int q=0;q<8;q++) idx[q]=csr[e+q];
        float4 v[8]; float dv[8];
        #pragma unroll
        for(int q=0;q<8;q++){ v[q]=bf4_to_f4(X4[(size_t)idx[q]*64+lane]); dv[q]=dinv[idx[q]]; }
        #pragma unroll
        for(int q=0;q<8;q++){
            acc.x = fmaf(dv[q],v[q].x,acc.x);
            acc.y = fmaf(dv[q],v[q].y,acc.y);
            acc.z = fmaf(dv[q],v[q].z,acc.z);
            acc.w = fmaf(dv[q],v[q].w,acc.w);
        }
    }
    if(e+4<=e1){
        int i0=csr[e], i1=csr[e+1], i2=csr[e+2], i3=csr[e+3];
        float4 v0 = bf4_to_f4(X4[(size_t)i0*64+lane]); float d0=dinv[i0];
        float4 v1 = bf4_to_f4(X4[(size_t)i1*64+lane]); float d1=dinv[i1];
        float4 v2 = bf4_to_f4(X4[(size_t)i2*64+lane]); float d2=dinv[i2];
        float4 v3 = bf4_to_f4(X4[(size_t)i3*64+lane]); float d3=dinv[i3];
        acc.x += d0*v0.x + d1*v1.x + d2*v2.x + d3*v3.x;
        acc.y += d0*v0.y + d1*v1.y + d2*v2.y + d3*v3.y;
        acc.z += d0*v0.z + d1*v1.z + d2*v2.z + d3*v3.z;
        acc.w += d0*v0.w + d1*v1.w + d2*v2.w + d3*v3.w;
        e += 4;
    }
    for(; e<e1; e++){
        int s = csr[e];
        float4 v = bf4_to_f4(X4[(size_t)s*64+lane]); float d=dinv[s];
        acc.x = fmaf(d,v.x,acc.x); acc.y = fmaf(d,v.y,acc.y);
        acc.z = fmaf(d,v.z,acc.z); acc.w = fmaf(d,v.w,acc.w);
    }
    ushort4 o; o.x=f2bf(dn*acc.x); o.y=f2bf(dn*acc.y); o.z=f2bf(dn*acc.z); o.w=f2bf(dn*acc.w);
    reinterpret_cast<ushort4*>(yb)[(size_t)n*64+lane] = o;
}

// epilogue for 16-row tiles. MODE: 0=INPUT (h0b=xb=o), 1=CONV (xb += 0.9o+0.1h0),
// 2=LAST (fout = xb + 0.9o + 0.1h0, fp32)
template<int MODE>
__device__ __forceinline__ void epilogue16(f32x4 (&acc)[4],
    const float* __restrict__ bp, const float* __restrict__ gp, const float* __restrict__ bep,
    ushort* __restrict__ h0b, ushort* __restrict__ xb, float* __restrict__ fout,
    int row0, int wc, int lr, int hi, int N,
    float (*sm1)[4], float (*sm2)[4])
{
    float bcv[4], gcv[4], bev[4];
    #pragma unroll
    for(int nf=0;nf<4;nf++){
        int col = wc*64 + nf*16 + lr;
        bcv[nf]=bp[col]; gcv[nf]=gp[col]; bev[nf]=bep[col];
    }
    #pragma unroll
    for(int r=0;r<4;r++){
        float ls1=0.f, ls2=0.f;
        #pragma unroll
        for(int nf=0;nf<4;nf++){
            float t = gelu_tanh(acc[nf][r] + bcv[nf]);
            acc[nf][r] = t;
            ls1 += t; ls2 += t*t;
        }
        #pragma unroll
        for(int off=1; off<16; off<<=1){
            ls1 += __shfl_xor(ls1, off, 64);
            ls2 += __shfl_xor(ls2, off, 64);
        }
        if(lr==0){
            int row = hi*4 + r;
            sm1[row][wc]=ls1; sm2[row][wc]=ls2;
        }
    }
    __syncthreads();
    #pragma unroll
    for(int r=0;r<4;r++){
        int row = hi*4 + r;
        int grow = row0 + row;
        if(grow >= N) continue;
        float S1 = sm1[row][0]+sm1[row][1]+sm1[row][2]+sm1[row][3];
        float S2 = sm2[row][0]+sm2[row][1]+sm2[row][2]+sm2[row][3];
        float mu = S1*(1.0f/256.0f);
        float var = fmaxf(S2*(1.0f/256.0f) - mu*mu, 0.0f);
        float rs = rsqrtf(var + 1e-5f);
        #pragma unroll
        for(int nf=0;nf<4;nf++){
            int col = wc*64 + nf*16 + lr;
            size_t idx = (size_t)grow*HID + col;
            float o = (acc[nf][r]-mu)*rs*gcv[nf] + bev[nf];
            if(MODE==0){
                ushort ob = f2bf(o);
                h0b[idx] = ob;
                xb[idx] = ob;
            }else{
                float xc = bf2f(xb[idx]) + 0.9f*o + 0.1f*bf2f(h0b[idx]);
                if(MODE==1) xb[idx] = f2bf(xc);
                else        fout[idx] = xc;
            }
        }
    }
}

// input block: 16-row tiles, reads fp32 X[N][128] directly, converts fragments in-reg
__global__ __launch_bounds__(256) void k_gemm_in(const float* __restrict__ X,
    const ushort* __restrict__ Wb,
    const float* __restrict__ bp, const float* __restrict__ gp, const float* __restrict__ bep,
    ushort* __restrict__ h0b, ushort* __restrict__ xb, int N)
{
    const int lane = threadIdx.x & 63;
    const int wc = threadIdx.x >> 6;
    const int lr = lane & 15;
    const int hi = lane >> 4;
    const int row0 = blockIdx.x*16;
    __shared__ float sm1[16][4];
    __shared__ float sm2[16][4];

    f32x4 acc[4];
    #pragma unroll
    for(int n=0;n<4;n++){ acc[n].x=0.f; acc[n].y=0.f; acc[n].z=0.f; acc[n].w=0.f; }

    int r0 = row0 + lr; if(r0 >= N) r0 = N-1;
    const float* xp0 = X + (size_t)r0*128 + hi*8;
    const ushort* bpp = Wb + (wc*64 + lr)*32 + hi*8;

    #pragma unroll
    for(int kb=0; kb<4; kb++){
        float4 p0a = *reinterpret_cast<const float4*>(xp0 + kb*32);
        float4 p0b = *reinterpret_cast<const float4*>(xp0 + kb*32 + 4);
        s16x8 a0;
        a0[0]=(short)f2bf(p0a.x); a0[1]=(short)f2bf(p0a.y); a0[2]=(short)f2bf(p0a.z); a0[3]=(short)f2bf(p0a.w);
        a0[4]=(short)f2bf(p0b.x); a0[5]=(short)f2bf(p0b.y); a0[6]=(short)f2bf(p0b.z); a0[7]=(short)f2bf(p0b.w);
        #pragma unroll
        for(int nf=0;nf<4;nf++){
            s16x8 b = *reinterpret_cast<const s16x8*>(bpp + kb*8192 + nf*512);
            acc[nf] = __builtin_amdgcn_mfma_f32_16x16x32_bf16(a0, b, acc[nf], 0,0,0);
        }
    }
    epilogue16<0>(acc, bp, gp, bep, h0b, xb, nullptr, row0, wc, lr, hi, N, sm1, sm2);
}

// conv GEMM: 16-row tiles, A = yb (aggregated bf16), fused bias/gelu/LN/blend
template<int MODE>
__global__ __launch_bounds__(256) void k_gemm_fused(const ushort* __restrict__ A,
    const ushort* __restrict__ Wb,
    const float* __restrict__ bp, const float* __restrict__ gp, const float* __restrict__ bep,
    ushort* __restrict__ h0b, ushort* __restrict__ xb, float* __restrict__ fout, int N)
{
    const int lane = threadIdx.x & 63;
    const int wc = threadIdx.x >> 6;
    const int lr = lane & 15;
    const int hi = lane >> 4;
    const int row0 = blockIdx.x*16;
    __shared__ float sm1[16][4];
    __shared__ float sm2[16][4];

    f32x4 acc[4];
    #pragma unroll
    for(int n=0;n<4;n++){ acc[n].x=0.f; acc[n].y=0.f; acc[n].z=0.f; acc[n].w=0.f; }

    int r0 = row0 + lr; if(r0 >= N) r0 = N-1;
    const ushort* ap0 = A + (size_t)r0*256 + hi*8;
    const ushort* bpp = Wb + (wc*64 + lr)*32 + hi*8;

    s16x8 a0[2], bb[2][4];
    a0[0] = *reinterpret_cast<const s16x8*>(ap0);
    #pragma unroll
    for(int nf=0;nf<4;nf++) bb[0][nf] = *reinterpret_cast<const s16x8*>(bpp + nf*512);

    #pragma unroll
    for(int kb=0; kb<8; kb++){
        const int cur = kb&1, nxt = cur^1;
        if(kb < 7){
            a0[nxt] = *reinterpret_cast<const s16x8*>(ap0 + (kb+1)*32);
            #pragma unroll
            for(int nf=0;nf<4;nf++)
                bb[nxt][nf] = *reinterpret_cast<const s16x8*>(bpp + (kb+1)*8192 + nf*512);
        }
        #pragma unroll
        for(int nf=0;nf<4;nf++)
            acc[nf] = __builtin_amdgcn_mfma_f32_16x16x32_bf16(a0[cur], bb[cur][nf], acc[nf], 0,0,0);
    }
    epilogue16<MODE>(acc, bp, gp, bep, h0b, xb, fout, row0, wc, lr, hi, N, sm1, sm2);
}

extern "C" void kernel_launch(void* const* d_in, const int* in_sizes, int n_in,
                              void* d_out, int out_size, void* d_ws, size_t ws_size,
                              hipStream_t stream){
    const float* x     = (const float*)d_in[0];
    const int*   ei    = (const int*)d_in[1];
    const float* W_in  = (const float*)d_in[2];
    const float* b_in  = (const float*)d_in[3];
    const float* g_in  = (const float*)d_in[4];
    const float* be_in = (const float*)d_in[5];
    const float* Wc    = (const float*)d_in[6];
    const float* bc    = (const float*)d_in[7];
    const float* gc    = (const float*)d_in[8];
    const float* bec   = (const float*)d_in[9];
    const int N = in_sizes[0]/128;
    const int E = in_sizes[1]/2;
    const int* src = ei;
    const int* dst = ei + E;
    float* fout = (float*)d_out;
    const int B = (N+1023)/1024;

    char* w = (char*)d_ws;
    ushort* xb   = (ushort*)w; w += (size_t)N*HID*2;
    ushort* yb   = (ushort*)w; w += (size_t)N*HID*2;
    ushort* h0b  = (ushort*)w; w += (size_t)N*HID*2;
    ushort* wbin = (ushort*)w; w += (size_t)128*256*2;
    ushort* wbc  = (ushort*)w; w += (size_t)6*65536*2;
    float* dinv  = (float*)w;  w += (size_t)N*4;
    int* cnt     = (int*)w;    w += (size_t)N*4;
    int* cursor  = (int*)w;    w += (size_t)N*4;
    int* csr     = (int*)w;    w += (size_t)E*4;
    int* indptr  = (int*)w;    w += (size_t)(N+1)*4;
    int* tsum    = (int*)w;    w += (size_t)B*256*4;
    int* bsum    = (int*)w;    w += (size_t)B*4;

    (void)hipMemsetAsync(cnt, 0, (size_t)N*4, stream);
    k_count<<<(E+255)/256,256,0,stream>>>(dst,cnt,E);
    k_scan1<<<B,256,0,stream>>>(cnt, tsum, bsum, N);
    k_scan3<<<B,256,0,stream>>>(cnt, tsum, bsum, indptr, cursor, dinv, N, B);
    k_fill<<<(E+255)/256,256,0,stream>>>(src,dst,cursor,csr,E);
    k_cvt_w<<<(32768+6*65536+255)/256,256,0,stream>>>(W_in, Wc, wbin, wbc);

    const int GB = (N+15)/16;
    k_gemm_in<<<GB,256,0,stream>>>(x, wbin, b_in, g_in, be_in, h0b, xb, N);
    for(int l=0;l<6;l++){
        k_agg<<<(N+3)/4,256,0,stream>>>(xb, indptr, csr, dinv, yb, N);
        if(l<5)
            k_gemm_fused<1><<<GB,256,0,stream>>>(yb, wbc+(size_t)l*65536,
                bc+(size_t)l*HID, gc+(size_t)l*HID, bec+(size_t)l*HID,
                h0b, xb, nullptr, N);
        else
            k_gemm_fused<2><<<GB,256,0,stream>>>(yb, wbc+(size_t)l*65536,
                bc+(size_t)l*HID, gc+(size_t)l*HID, bec+(size_t)l*HID,
                h0b, xb, fout, N);
    }
}